// Round 15
// baseline (836.973 us; speedup 1.0000x reference)
//
#include <hip/hip_runtime.h>
#include <type_traits>

typedef unsigned short u16;
typedef _Float16 f16;
typedef f16 f16x8 __attribute__((ext_vector_type(8)));
typedef unsigned short u16x8 __attribute__((ext_vector_type(8)));
typedef unsigned short u16x4 __attribute__((ext_vector_type(4)));
typedef float f32x4 __attribute__((ext_vector_type(4)));

#define DEV __device__ __forceinline__

DEV u16 f2h(float f) { return __builtin_bit_cast(u16, (f16)f); }  // RNE
DEV float h2f(u16 u) { return (float)__builtin_bit_cast(f16, u); }

DEV f32x4 mfma_f16(f16x8 a, f16x8 b, f32x4 c) {
  return __builtin_amdgcn_mfma_f32_16x16x32_f16(a, b, c, 0, 0, 0);
}
DEV f16x8 ldf16(const u16* p) { return *(const f16x8*)p; }

DEV void gl2lds16(const u16* g, u16* l) {
  __builtin_amdgcn_global_load_lds((const __attribute__((address_space(1))) void*)g,
                                   (__attribute__((address_space(3))) void*)l, 16, 0, 0);
}

// LDS tile [rows][64 u16], XOR-swizzled: physical col = col ^ ((row&7)<<3).
DEV int swz(int row, int col) { return row * 64 + (col ^ ((row & 7) << 3)); }

// XCD-chunked remap (nwg % 8 == 0): each XCD owns a contiguous work chunk.
DEV int xcd_remap(int d, int nwg) { return (d & 7) * (nwg >> 3) + (d >> 3); }

// ---------------- all four weights: transpose fp32 -> fp16 in one launch ----------------
__global__ __launch_bounds__(256)
void wT_all_kernel(const float* __restrict__ Wq_t, const float* __restrict__ Wo_t,
                   const float* __restrict__ Wq_s, const float* __restrict__ Wo_s,
                   u16* __restrict__ Tq_t, u16* __restrict__ To_t,
                   u16* __restrict__ Tq_s, u16* __restrict__ To_s) {
  const int bid = blockIdx.x;
  const float* W;
  u16* T;
  int N, base;
  if (bid < 768)       { W = Wq_t; T = Tq_t; N = 1536; base = bid; }
  else if (bid < 1024) { W = Wo_t; T = To_t; N = 512;  base = bid - 768; }
  else if (bid < 1792) { W = Wq_s; T = Tq_s; N = 1536; base = bid - 1024; }
  else                 { W = Wo_s; T = To_s; N = 512;  base = bid - 1792; }
#pragma unroll
  for (int j = 0; j < 4; ++j) {
    int i = base * 1024 + j * 256 + threadIdx.x;
    int n = i >> 9, k = i & 511;
    T[i] = f2h(W[(size_t)k * N + n]);
  }
}

// ---------------- fused LayerNorm (rows of 512 fp32) -> fp16 ----------------
__global__ __launch_bounds__(256)
void ln_kernel(const float* __restrict__ X, const float* __restrict__ G,
               const float* __restrict__ B, u16* __restrict__ H) {
  const int row = (blockIdx.x << 2) + (threadIdx.x >> 6);
  const int l = threadIdx.x & 63;
  const float* x = X + ((size_t)row << 9) + l * 8;
  float v[8];
  *(float4*)&v[0] = *(const float4*)(x);
  *(float4*)&v[4] = *(const float4*)(x + 4);
  float s = 0.f, s2 = 0.f;
#pragma unroll
  for (int e = 0; e < 8; ++e) { s += v[e]; s2 += v[e] * v[e]; }
#pragma unroll
  for (int o = 1; o < 64; o <<= 1) { s += __shfl_xor(s, o, 64); s2 += __shfl_xor(s2, o, 64); }
  const float mean = s * (1.f / 512.f);
  const float rs = rsqrtf(s2 * (1.f / 512.f) - mean * mean + 1e-5f);
  float g[8], bb[8];
  *(float4*)&g[0] = *(const float4*)(G + l * 8);
  *(float4*)&g[4] = *(const float4*)(G + l * 8 + 4);
  *(float4*)&bb[0] = *(const float4*)(B + l * 8);
  *(float4*)&bb[4] = *(const float4*)(B + l * 8 + 4);
  u16x8 o8;
#pragma unroll
  for (int e = 0; e < 8; ++e) o8[e] = f2h((v[e] - mean) * rs * g[e] + bb[e]);
  *(u16x8*)(H + ((size_t)row << 9) + l * 8) = o8;
}

// ---------------- LayerNorm on fp16 rows of 512 -> fp16 ----------------
__global__ __launch_bounds__(256)
void ln16_kernel(const u16* __restrict__ X, const float* __restrict__ G,
                 const float* __restrict__ B, u16* __restrict__ H) {
  const int row = (blockIdx.x << 2) + (threadIdx.x >> 6);
  const int l = threadIdx.x & 63;
  u16x8 raw = *(const u16x8*)(X + ((size_t)row << 9) + l * 8);
  float v[8];
#pragma unroll
  for (int e = 0; e < 8; ++e) v[e] = h2f(raw[e]);
  float s = 0.f, s2 = 0.f;
#pragma unroll
  for (int e = 0; e < 8; ++e) { s += v[e]; s2 += v[e] * v[e]; }
#pragma unroll
  for (int o = 1; o < 64; o <<= 1) { s += __shfl_xor(s, o, 64); s2 += __shfl_xor(s2, o, 64); }
  const float mean = s * (1.f / 512.f);
  const float rs = rsqrtf(s2 * (1.f / 512.f) - mean * mean + 1e-5f);
  float g[8], bb[8];
  *(float4*)&g[0] = *(const float4*)(G + l * 8);
  *(float4*)&g[4] = *(const float4*)(G + l * 8 + 4);
  *(float4*)&bb[0] = *(const float4*)(B + l * 8);
  *(float4*)&bb[4] = *(const float4*)(B + l * 8 + 4);
  u16x8 o8;
#pragma unroll
  for (int e = 0; e < 8; ++e) o8[e] = f2h((v[e] - mean) * rs * g[e] + bb[e]);
  *(u16x8*)(H + ((size_t)row << 9) + l * 8) = o8;
}

// ---------------- qkv GEMM (temporal): round-11 form, proven 80 VGPR ----------------
template <int K>
__global__ __launch_bounds__(256)
void gemm_qkv(const u16* __restrict__ A, const u16* __restrict__ Bt,
              u16* __restrict__ Cq, u16* __restrict__ Cv, int lda, int ldb) {
  __shared__ u16 lds[2 * 128 * 64];  // lsA | lsB; reused as epilogue bounce [64][136]
  u16* lsA = lds;
  u16* lsB = lds + 128 * 64;
  const int tid = threadIdx.x;
  const int w = tid >> 6, l = tid & 63;
  const int lr = l & 15, lg = l >> 4;
  const int wm = w >> 1, wn = w & 1;
  const int gx = gridDim.x;
  const int wk = xcd_remap(blockIdx.y * gx + blockIdx.x, gx * gridDim.y);
  const int Row0 = (wk / gx) * 128, Col0 = (wk % gx) * 128;
  const int gcol = ((l & 7) ^ (l >> 3)) * 8;

  const int srow = w * 32 + (l >> 3);
  const u16* baseA = A + (size_t)(Row0 + srow) * lda + gcol;
  const u16* baseB = Bt + (size_t)(Col0 + srow) * ldb + gcol;

  f32x4 acc[4][4];
  const f32x4 zero = {0.f, 0.f, 0.f, 0.f};
#pragma unroll
  for (int m = 0; m < 4; ++m)
#pragma unroll
    for (int n = 0; n < 4; ++n) acc[m][n] = zero;

#pragma unroll
  for (int k0 = 0; k0 < K; k0 += 64) {
    __syncthreads();
#pragma unroll
    for (int i = 0; i < 4; ++i) {
      gl2lds16(baseA + (size_t)(i * 8) * lda + k0, &lsA[w * 2048 + i * 512]);
      gl2lds16(baseB + (size_t)(i * 8) * ldb + k0, &lsB[w * 2048 + i * 512]);
    }
    __syncthreads();
#pragma unroll
    for (int kk = 0; kk < 64; kk += 32) {
      f16x8 af[4], bfv[4];
#pragma unroll
      for (int m = 0; m < 4; ++m)
        af[m] = ldf16(&lsA[swz(wm * 64 + m * 16 + lr, kk + 8 * lg)]);
#pragma unroll
      for (int n = 0; n < 4; ++n)
        bfv[n] = ldf16(&lsB[swz(wn * 64 + n * 16 + lr, kk + 8 * lg)]);
#pragma unroll
      for (int m = 0; m < 4; ++m)
#pragma unroll
        for (int n = 0; n < 4; ++n) acc[m][n] = mfma_f16(af[m], bfv[n], acc[m][n]);
    }
  }

  const bool isV = (Col0 >= 1024);
#pragma unroll
  for (int p = 0; p < 2; ++p) {
    __syncthreads();
    if (wm == p) {
#pragma unroll
      for (int m = 0; m < 4; ++m)
#pragma unroll
        for (int n = 0; n < 4; ++n) {
          int col = wn * 64 + n * 16 + lr;
#pragma unroll
          for (int r = 0; r < 4; ++r)
            lds[(m * 16 + lg * 4 + r) * 136 + col] = f2h(acc[m][n][r]);
        }
    }
    __syncthreads();
#pragma unroll
    for (int it = 0; it < 4; ++it) {
      int cid = it * 256 + tid;
      int rl = cid >> 4, cc = (cid & 15) * 8;
      u16x8 vv = *(u16x8*)&lds[rl * 136 + cc];
      int gr = Row0 + p * 64 + rl;
      int gc = Col0 + cc;
      if (!isV)
        *(u16x8*)&Cq[(size_t)gr * 1024 + gc] = vv;
      else
        *(u16x8*)&Cv[(size_t)gr * 512 + gc - 1024] = vv;
    }
  }
}

// ---------------- qkv GEMM (spatial): separate clone; V written TRANSPOSED ----------------
// Q epilogue identical; V epilogue -> Vt[bt][d][c] (indexing verified in round 12's pass).
template <int K>
__global__ __launch_bounds__(256)
void gemm_qkv_vt(const u16* __restrict__ A, const u16* __restrict__ Bt,
                 u16* __restrict__ Cq, u16* __restrict__ Vt, int lda, int ldb) {
  __shared__ u16 lds[2 * 128 * 64];
  u16* lsA = lds;
  u16* lsB = lds + 128 * 64;
  const int tid = threadIdx.x;
  const int w = tid >> 6, l = tid & 63;
  const int lr = l & 15, lg = l >> 4;
  const int wm = w >> 1, wn = w & 1;
  const int gx = gridDim.x;
  const int wk = xcd_remap(blockIdx.y * gx + blockIdx.x, gx * gridDim.y);
  const int Row0 = (wk / gx) * 128, Col0 = (wk % gx) * 128;
  const int gcol = ((l & 7) ^ (l >> 3)) * 8;

  const int srow = w * 32 + (l >> 3);
  const u16* baseA = A + (size_t)(Row0 + srow) * lda + gcol;
  const u16* baseB = Bt + (size_t)(Col0 + srow) * ldb + gcol;

  f32x4 acc[4][4];
  const f32x4 zero = {0.f, 0.f, 0.f, 0.f};
#pragma unroll
  for (int m = 0; m < 4; ++m)
#pragma unroll
    for (int n = 0; n < 4; ++n) acc[m][n] = zero;

#pragma unroll
  for (int k0 = 0; k0 < K; k0 += 64) {
    __syncthreads();
#pragma unroll
    for (int i = 0; i < 4; ++i) {
      gl2lds16(baseA + (size_t)(i * 8) * lda + k0, &lsA[w * 2048 + i * 512]);
      gl2lds16(baseB + (size_t)(i * 8) * ldb + k0, &lsB[w * 2048 + i * 512]);
    }
    __syncthreads();
#pragma unroll
    for (int kk = 0; kk < 64; kk += 32) {
      f16x8 af[4], bfv[4];
#pragma unroll
      for (int m = 0; m < 4; ++m)
        af[m] = ldf16(&lsA[swz(wm * 64 + m * 16 + lr, kk + 8 * lg)]);
#pragma unroll
      for (int n = 0; n < 4; ++n)
        bfv[n] = ldf16(&lsB[swz(wn * 64 + n * 16 + lr, kk + 8 * lg)]);
#pragma unroll
      for (int m = 0; m < 4; ++m)
#pragma unroll
        for (int n = 0; n < 4; ++n) acc[m][n] = mfma_f16(af[m], bfv[n], acc[m][n]);
    }
  }

  if (Col0 >= 1024) {
    // V transposed: tile = c [Row0&1023,+128) x d [Col0-1024,+128); Vt[bt][d][c]
    const int bt = Row0 >> 10;
    const int c0 = Row0 & 1023;
    const int d0 = Col0 - 1024;
#pragma unroll
    for (int p = 0; p < 2; ++p) {
      __syncthreads();
      if (wm == p) {
#pragma unroll
        for (int m = 0; m < 4; ++m)
#pragma unroll
          for (int n = 0; n < 4; ++n) {
            int col = wn * 64 + n * 16 + lr;  // d_local
#pragma unroll
            for (int r = 0; r < 4; ++r)
              lds[col * 72 + m * 16 + lg * 4 + r] = f2h(acc[m][n][r]);  // [d][c] pad 72
          }
      }
      __syncthreads();
#pragma unroll
      for (int it = 0; it < 4; ++it) {
        int cid = it * 256 + tid;
        int dl = cid >> 3, cc = (cid & 7) * 8;
        u16x8 vv = *(u16x8*)&lds[dl * 72 + cc];
        *(u16x8*)&Vt[(size_t)bt * 524288 + (size_t)(d0 + dl) * 1024 + c0 + p * 64 + cc] = vv;
      }
    }
    return;
  }
#pragma unroll
  for (int p = 0; p < 2; ++p) {
    __syncthreads();
    if (wm == p) {
#pragma unroll
      for (int m = 0; m < 4; ++m)
#pragma unroll
        for (int n = 0; n < 4; ++n) {
          int col = wn * 64 + n * 16 + lr;
#pragma unroll
          for (int r = 0; r < 4; ++r)
            lds[(m * 16 + lg * 4 + r) * 136 + col] = f2h(acc[m][n][r]);
        }
    }
    __syncthreads();
#pragma unroll
    for (int it = 0; it < 4; ++it) {
      int cid = it * 256 + tid;
      int rl = cid >> 4, cc = (cid & 15) * 8;
      u16x8 vv = *(u16x8*)&lds[rl * 136 + cc];
      *(u16x8*)&Cq[(size_t)(Row0 + p * 64 + rl) * 1024 + Col0 + cc] = vv;
    }
  }
}

// ---------------- fp16 GEMM 128x128xK (unrolled), A[M,K], B^T[N,K], batched ----------------
// REMAP: 0 none, 1 = 2D XCD remap, 2 = 3D flatten+XCD remap (batched ops).
template <bool OUT16, int REMAP, int K>
__global__ __launch_bounds__(256)
void gemm_bt(const u16* __restrict__ A, const u16* __restrict__ Bt,
             void* __restrict__ Cp, const float* __restrict__ bias,
             int lda, int ldb, int ldc,
             long long sA, long long sB, long long sC, float scale) {
  __shared__ u16 lds[2 * 128 * 64];
  u16* lsA = lds;
  u16* lsB = lds + 128 * 64;
  const int tid = threadIdx.x;
  const int w = tid >> 6, l = tid & 63;
  const int lr = l & 15, lg = l >> 4;
  const int wm = w >> 1, wn = w & 1;
  int Row0, Col0, bz;
  if constexpr (REMAP == 1) {
    const int gx = gridDim.x;
    const int wk = xcd_remap(blockIdx.y * gx + blockIdx.x, gx * gridDim.y);
    Row0 = (wk / gx) * 128; Col0 = (wk % gx) * 128; bz = blockIdx.z;
  } else if constexpr (REMAP == 2) {
    const int gx = gridDim.x, gy = gridDim.y;
    const int d = blockIdx.x + gx * (blockIdx.y + gy * blockIdx.z);
    const int wk = xcd_remap(d, gx * gy * gridDim.z);
    Col0 = (wk % gx) * 128;
    int rest = wk / gx;
    Row0 = (rest % gy) * 128;
    bz = rest / gy;
  } else {
    Row0 = blockIdx.y * 128; Col0 = blockIdx.x * 128; bz = blockIdx.z;
  }
  const int gcol = ((l & 7) ^ (l >> 3)) * 8;

  const int srow = w * 32 + (l >> 3);
  const u16* baseA = A + (size_t)bz * sA + (size_t)(Row0 + srow) * lda + gcol;
  const u16* baseB = Bt + (size_t)bz * sB + (size_t)(Col0 + srow) * ldb + gcol;

  f32x4 acc[4][4];
  const f32x4 zero = {0.f, 0.f, 0.f, 0.f};
#pragma unroll
  for (int m = 0; m < 4; ++m)
#pragma unroll
    for (int n = 0; n < 4; ++n) acc[m][n] = zero;

#pragma unroll
  for (int k0 = 0; k0 < K; k0 += 64) {
    __syncthreads();
#pragma unroll
    for (int i = 0; i < 4; ++i) {
      gl2lds16(baseA + (size_t)(i * 8) * lda + k0, &lsA[w * 2048 + i * 512]);
      gl2lds16(baseB + (size_t)(i * 8) * ldb + k0, &lsB[w * 2048 + i * 512]);
    }
    __syncthreads();
#pragma unroll
    for (int kk = 0; kk < 64; kk += 32) {
      f16x8 af[4], bfv[4];
#pragma unroll
      for (int m = 0; m < 4; ++m)
        af[m] = ldf16(&lsA[swz(wm * 64 + m * 16 + lr, kk + 8 * lg)]);
#pragma unroll
      for (int n = 0; n < 4; ++n)
        bfv[n] = ldf16(&lsB[swz(wn * 64 + n * 16 + lr, kk + 8 * lg)]);
#pragma unroll
      for (int m = 0; m < 4; ++m)
#pragma unroll
        for (int n = 0; n < 4; ++n) acc[m][n] = mfma_f16(af[m], bfv[n], acc[m][n]);
    }
  }

  if constexpr (OUT16) {
    u16* Cb = (u16*)Cp + (size_t)bz * sC;
#pragma unroll
    for (int p = 0; p < 2; ++p) {
      __syncthreads();
      if (wm == p) {
#pragma unroll
        for (int m = 0; m < 4; ++m)
#pragma unroll
          for (int n = 0; n < 4; ++n) {
            int col = wn * 64 + n * 16 + lr;
            float bv = bias ? bias[Col0 + col] : 0.f;
#pragma unroll
            for (int r = 0; r < 4; ++r)
              lds[(m * 16 + lg * 4 + r) * 136 + col] = f2h(acc[m][n][r] * scale + bv);
          }
      }
      __syncthreads();
#pragma unroll
      for (int it = 0; it < 4; ++it) {
        int cid = it * 256 + tid;
        int rl = cid >> 4, cc = (cid & 15) * 8;
        u16x8 vv = *(u16x8*)&lds[rl * 136 + cc];
        *(u16x8*)&Cb[(size_t)(Row0 + p * 64 + rl) * ldc + Col0 + cc] = vv;
      }
    }
  } else {
    float* Cb = (float*)Cp + (size_t)bz * sC;
    float* ldsF = (float*)lds;  // [32][132] fp32
#pragma unroll
    for (int q = 0; q < 4; ++q) {
      __syncthreads();
      if (wm == (q >> 1)) {
        int mBase = (q & 1) * 2;
#pragma unroll
        for (int mi = 0; mi < 2; ++mi) {
          int m = mBase + mi;
#pragma unroll
          for (int n = 0; n < 4; ++n) {
            int col = wn * 64 + n * 16 + lr;
            float bv = bias ? bias[Col0 + col] : 0.f;
#pragma unroll
            for (int r = 0; r < 4; ++r)
              ldsF[(mi * 16 + lg * 4 + r) * 132 + col] = acc[m][n][r] * scale + bv;
          }
        }
      }
      __syncthreads();
#pragma unroll
      for (int it = 0; it < 4; ++it) {
        int cid = it * 256 + tid;
        int rw = cid >> 5, c4 = (cid & 31) * 4;
        float4 v = *(float4*)&ldsF[rw * 132 + c4];
        *(float4*)&Cb[(size_t)(Row0 + q * 32 + rw) * ldc + Col0 + c4] = v;
      }
    }
  }
}

// ---------------- fused temporal attention (fp16), one block per (b,c) ----------------
__global__ __launch_bounds__(256)
void attn_t_kernel(const u16* __restrict__ QK, const u16* __restrict__ Vb,
                   u16* __restrict__ O) {
  __shared__ u16 qs[32 * 520];
  __shared__ u16 ks[32 * 520];
  __shared__ u16 vT[512 * 40];
  __shared__ float Sf[32 * 36];
  __shared__ u16 Pf[32 * 40];

  const int tid = threadIdx.x;
  const int bc = blockIdx.x;  // b*1024 + c
  const int w = tid >> 6, l = tid & 63, lr = l & 15, lg = l >> 4;
  const int wr = w >> 1, wc = w & 1;
  const size_t base = (size_t)(bc >> 10) * 32768 + (bc & 1023);

#pragma unroll
  for (int i = 0; i < 8; ++i) {
    int t = w * 8 + i;
    const u16* rb = QK + (base + (size_t)t * 1024) * 1024;
    gl2lds16(rb + l * 8, &qs[t * 520]);
    gl2lds16(rb + 512 + l * 8, &ks[t * 520]);
  }
  {  // V staging, t-major lanes: conflict-free vT writes
    const int t = tid & 31;
    const int db0 = (tid >> 5) * 8;
    const u16* vrow = Vb + (base + (size_t)t * 1024) * 512;
#pragma unroll
    for (int j = 0; j < 8; ++j) {
      int db = db0 + j;
      u16x8 vv = *(const u16x8*)(vrow + db * 8);
#pragma unroll
      for (int e = 0; e < 8; ++e) vT[(db * 8 + e) * 40 + t] = vv[e];
    }
  }
  __syncthreads();

  f32x4 sacc = {0.f, 0.f, 0.f, 0.f};
#pragma unroll
  for (int kk = 0; kk < 512; kk += 32)
    sacc = mfma_f16(ldf16(&qs[(wr * 16 + lr) * 520 + kk + 8 * lg]),
                    ldf16(&ks[(wc * 16 + lr) * 520 + kk + 8 * lg]), sacc);
#pragma unroll
  for (int r = 0; r < 4; ++r)
    Sf[(wr * 16 + lg * 4 + r) * 36 + wc * 16 + lr] = sacc[r] * 0.125f;
  __syncthreads();

  {  // parallel softmax: 8 threads per row
    const int row = tid >> 3, c0 = (tid & 7) * 4;
    float4 sv = *(float4*)&Sf[row * 36 + c0];
    float mx = fmaxf(fmaxf(sv.x, sv.y), fmaxf(sv.z, sv.w));
#pragma unroll
    for (int o = 1; o < 8; o <<= 1) mx = fmaxf(mx, __shfl_xor(mx, o, 64));
    float e0 = __expf(sv.x - mx), e1 = __expf(sv.y - mx);
    float e2 = __expf(sv.z - mx), e3 = __expf(sv.w - mx);
    float sum = e0 + e1 + e2 + e3;
#pragma unroll
    for (int o = 1; o < 8; o <<= 1) sum += __shfl_xor(sum, o, 64);
    float inv = 1.f / sum;
    u16x4 p4 = {f2h(e0 * inv), f2h(e1 * inv), f2h(e2 * inv), f2h(e3 * inv)};
    *(u16x4*)&Pf[row * 40 + c0] = p4;
  }
  __syncthreads();

  {  // O = P @ V, staged into qs for coalesced u16x8 stores
    const int mr = w >> 1, nh = w & 1;
    f16x8 ap = ldf16(&Pf[(mr * 16 + lr) * 40 + 8 * lg]);
#pragma unroll
    for (int j = 0; j < 16; ++j) {
      int nc = (nh * 16 + j) * 16;
      f32x4 o = {0.f, 0.f, 0.f, 0.f};
      o = mfma_f16(ap, ldf16(&vT[(nc + lr) * 40 + 8 * lg]), o);
#pragma unroll
      for (int r = 0; r < 4; ++r)
        qs[(mr * 16 + lg * 4 + r) * 520 + nc + lr] = f2h(o[r]);
    }
  }
  __syncthreads();
#pragma unroll
  for (int it = 0; it < 8; ++it) {
    int cid = it * 256 + tid;
    int t = cid >> 6, col = (cid & 63) * 8;
    u16x8 vv = *(u16x8*)&qs[t * 520 + col];
    *(u16x8*)&O[(base + (size_t)t * 1024) * 512 + col] = vv;
  }
}

// ---------------- row softmax over 1024 fp16, in place ----------------
__global__ __launch_bounds__(256)
void softmax16_kernel(u16* __restrict__ S) {
  u16* p = S + ((size_t)blockIdx.x << 10);
  const int tid = threadIdx.x, w = tid >> 6, l = tid & 63;
  __shared__ float red[8];
  u16x4 raw = *(u16x4*)&p[tid << 2];
  float v0 = h2f(raw[0]), v1 = h2f(raw[1]), v2 = h2f(raw[2]), v3 = h2f(raw[3]);
  float m = fmaxf(fmaxf(v0, v1), fmaxf(v2, v3));
#pragma unroll
  for (int o = 1; o < 64; o <<= 1) m = fmaxf(m, __shfl_xor(m, o, 64));
  if (l == 0) red[w] = m;
  __syncthreads();
  m = fmaxf(fmaxf(red[0], red[1]), fmaxf(red[2], red[3]));
  v0 = __expf(v0 - m); v1 = __expf(v1 - m); v2 = __expf(v2 - m); v3 = __expf(v3 - m);
  float s = v0 + v1 + v2 + v3;
#pragma unroll
  for (int o = 1; o < 64; o <<= 1) s += __shfl_xor(s, o, 64);
  if (l == 0) red[4 + w] = s;
  __syncthreads();
  const float inv = 1.f / (red[4] + red[5] + red[6] + red[7]);
  u16x4 o4 = {f2h(v0 * inv), f2h(v1 * inv), f2h(v2 * inv), f2h(v3 * inv)};
  *(u16x4*)&p[tid << 2] = o4;
}

extern "C" void kernel_launch(void* const* d_in, const int* in_sizes, int n_in,
                              void* d_out, int out_size, void* d_ws, size_t ws_size,
                              hipStream_t stream) {
  (void)in_sizes; (void)n_in; (void)out_size; (void)ws_size;
  const float* x      = (const float*)d_in[0];
  const float* gam_t  = (const float*)d_in[1];
  const float* bet_t  = (const float*)d_in[2];
  const float* wqkv_t = (const float*)d_in[3];
  const float* wout_t = (const float*)d_in[4];
  const float* bout_t = (const float*)d_in[5];
  const float* gam_s  = (const float*)d_in[6];
  const float* bet_s  = (const float*)d_in[7];
  const float* wqkv_s = (const float*)d_in[8];
  const float* wout_s = (const float*)d_in[9];
  const float* bout_s = (const float*)d_in[10];
  float* out = (float*)d_out;

  char* ws = (char*)d_ws;
  size_t off = 0;
  auto alloc = [&](size_t bytes) -> char* {
    char* p = ws + off;
    off = (off + bytes + 255) & ~(size_t)255;
    return p;
  };
  // Total ~324 MiB. Aliases: h = S region; out1 = QK first half; Vt = Vb slot.
  u16* wqkvT_t = (u16*)alloc((size_t)1536 * 512 * 2);
  u16* woutT_t = (u16*)alloc((size_t)512 * 512 * 2);
  u16* wqkvT_s = (u16*)alloc((size_t)1536 * 512 * 2);
  u16* woutT_s = (u16*)alloc((size_t)512 * 512 * 2);
  u16* QK      = (u16*)alloc((size_t)65536 * 1024 * 2);      // 128 MiB
  u16* Vb      = (u16*)alloc((size_t)65536 * 512 * 2);       //  64 MiB (temporal V / spatial Vt)
  u16* attnO   = (u16*)alloc((size_t)65536 * 512 * 2);       //  64 MiB
  u16* S       = (u16*)alloc((size_t)32 * 1024 * 1024 * 2);  //  64 MiB (32-batch chunk)
  u16* h       = S;    // LN output (64 MiB), dead before S is written
  u16* out1    = QK;   // temporal block output fp16 (64 MiB)
  u16* Vt      = Vb;   // spatial V transposed [bt][512][1024]

  const dim3 blk(256);

  wT_all_kernel<<<2048, blk, 0, stream>>>(wqkv_t, wout_t, wqkv_s, wout_s,
                                          wqkvT_t, woutT_t, wqkvT_s, woutT_s);

  // ---- temporal ----
  ln_kernel<<<16384, blk, 0, stream>>>(x, gam_t, bet_t, h);
  gemm_qkv<512><<<dim3(12, 512, 1), blk, 0, stream>>>(h, wqkvT_t, QK, Vb, 512, 512);
  attn_t_kernel<<<2048, blk, 0, stream>>>(QK, Vb, attnO);
  gemm_bt<true, 1, 512><<<dim3(4, 512, 1), blk, 0, stream>>>(
      attnO, woutT_t, out1, bout_t, 512, 512, 512, 0, 0, 0, 1.f);

  // ---- spatial (V written transposed by gemm_qkv_vt; no transpose_v pass) ----
  ln16_kernel<<<16384, blk, 0, stream>>>(out1, gam_s, bet_s, h);
  gemm_qkv_vt<512><<<dim3(12, 512, 1), blk, 0, stream>>>(h, wqkvT_s, QK, Vt, 512, 512);

  for (int ch = 0; ch < 2; ++ch) {  // 32 (b,t) batches per chunk
    const u16* qkc = QK + (size_t)ch * 32 * 1024 * 1024;
    const u16* vtc = Vt + (size_t)ch * 32 * 512 * 1024;
    u16* attc = attnO + (size_t)ch * 32 * 1024 * 512;
    gemm_bt<true, 2, 512><<<dim3(8, 8, 32), blk, 0, stream>>>(
        qkc, qkc + 512, S, nullptr, 1024, 1024, 1024,
        1024LL * 1024, 1024LL * 1024, 1024LL * 1024, 0.125f);
    softmax16_kernel<<<32768, blk, 0, stream>>>(S);
    gemm_bt<true, 2, 1024><<<dim3(4, 8, 32), blk, 0, stream>>>(
        S, vtc, attc, nullptr, 1024, 1024, 512,
        1024LL * 1024, 512LL * 1024, 1024LL * 512, 1.f);
  }

  gemm_bt<false, 1, 512><<<dim3(4, 512, 1), blk, 0, stream>>>(
      attnO, woutT_s, out, bout_s, 512, 512, 512, 0, 0, 0, 1.f);
}

// Round 16
// 798.433 us; speedup vs baseline: 1.0483x; 1.0483x over previous
//
#include <hip/hip_runtime.h>
#include <type_traits>

typedef unsigned short u16;
typedef _Float16 f16;
typedef f16 f16x8 __attribute__((ext_vector_type(8)));
typedef unsigned short u16x8 __attribute__((ext_vector_type(8)));
typedef unsigned short u16x4 __attribute__((ext_vector_type(4)));
typedef float f32x4 __attribute__((ext_vector_type(4)));

#define DEV __device__ __forceinline__

DEV u16 f2h(float f) { return __builtin_bit_cast(u16, (f16)f); }  // RNE
DEV float h2f(u16 u) { return (float)__builtin_bit_cast(f16, u); }

DEV f32x4 mfma_f16(f16x8 a, f16x8 b, f32x4 c) {
  return __builtin_amdgcn_mfma_f32_16x16x32_f16(a, b, c, 0, 0, 0);
}
DEV f16x8 ldf16(const u16* p) { return *(const f16x8*)p; }

DEV void gl2lds16(const u16* g, u16* l) {
  __builtin_amdgcn_global_load_lds((const __attribute__((address_space(1))) void*)g,
                                   (__attribute__((address_space(3))) void*)l, 16, 0, 0);
}

// LDS tile [rows][64 u16], XOR-swizzled: physical col = col ^ ((row&7)<<3).
DEV int swz(int row, int col) { return row * 64 + (col ^ ((row & 7) << 3)); }

// XCD-chunked remap (nwg % 8 == 0): each XCD owns a contiguous work chunk.
DEV int xcd_remap(int d, int nwg) { return (d & 7) * (nwg >> 3) + (d >> 3); }

// ---------------- all four weights: transpose fp32 -> fp16 in one launch ----------------
__global__ __launch_bounds__(256)
void wT_all_kernel(const float* __restrict__ Wq_t, const float* __restrict__ Wo_t,
                   const float* __restrict__ Wq_s, const float* __restrict__ Wo_s,
                   u16* __restrict__ Tq_t, u16* __restrict__ To_t,
                   u16* __restrict__ Tq_s, u16* __restrict__ To_s) {
  const int bid = blockIdx.x;
  const float* W;
  u16* T;
  int N, base;
  if (bid < 768)       { W = Wq_t; T = Tq_t; N = 1536; base = bid; }
  else if (bid < 1024) { W = Wo_t; T = To_t; N = 512;  base = bid - 768; }
  else if (bid < 1792) { W = Wq_s; T = Tq_s; N = 1536; base = bid - 1024; }
  else                 { W = Wo_s; T = To_s; N = 512;  base = bid - 1792; }
#pragma unroll
  for (int j = 0; j < 4; ++j) {
    int i = base * 1024 + j * 256 + threadIdx.x;
    int n = i >> 9, k = i & 511;
    T[i] = f2h(W[(size_t)k * N + n]);
  }
}

// ---------------- fused LayerNorm (rows of 512 fp32) -> fp16 ----------------
__global__ __launch_bounds__(256)
void ln_kernel(const float* __restrict__ X, const float* __restrict__ G,
               const float* __restrict__ B, u16* __restrict__ H) {
  const int row = (blockIdx.x << 2) + (threadIdx.x >> 6);
  const int l = threadIdx.x & 63;
  const float* x = X + ((size_t)row << 9) + l * 8;
  float v[8];
  *(float4*)&v[0] = *(const float4*)(x);
  *(float4*)&v[4] = *(const float4*)(x + 4);
  float s = 0.f, s2 = 0.f;
#pragma unroll
  for (int e = 0; e < 8; ++e) { s += v[e]; s2 += v[e] * v[e]; }
#pragma unroll
  for (int o = 1; o < 64; o <<= 1) { s += __shfl_xor(s, o, 64); s2 += __shfl_xor(s2, o, 64); }
  const float mean = s * (1.f / 512.f);
  const float rs = rsqrtf(s2 * (1.f / 512.f) - mean * mean + 1e-5f);
  float g[8], bb[8];
  *(float4*)&g[0] = *(const float4*)(G + l * 8);
  *(float4*)&g[4] = *(const float4*)(G + l * 8 + 4);
  *(float4*)&bb[0] = *(const float4*)(B + l * 8);
  *(float4*)&bb[4] = *(const float4*)(B + l * 8 + 4);
  u16x8 o8;
#pragma unroll
  for (int e = 0; e < 8; ++e) o8[e] = f2h((v[e] - mean) * rs * g[e] + bb[e]);
  *(u16x8*)(H + ((size_t)row << 9) + l * 8) = o8;
}

// ---------------- LayerNorm on fp16 rows of 512 -> fp16 ----------------
__global__ __launch_bounds__(256)
void ln16_kernel(const u16* __restrict__ X, const float* __restrict__ G,
                 const float* __restrict__ B, u16* __restrict__ H) {
  const int row = (blockIdx.x << 2) + (threadIdx.x >> 6);
  const int l = threadIdx.x & 63;
  u16x8 raw = *(const u16x8*)(X + ((size_t)row << 9) + l * 8);
  float v[8];
#pragma unroll
  for (int e = 0; e < 8; ++e) v[e] = h2f(raw[e]);
  float s = 0.f, s2 = 0.f;
#pragma unroll
  for (int e = 0; e < 8; ++e) { s += v[e]; s2 += v[e] * v[e]; }
#pragma unroll
  for (int o = 1; o < 64; o <<= 1) { s += __shfl_xor(s, o, 64); s2 += __shfl_xor(s2, o, 64); }
  const float mean = s * (1.f / 512.f);
  const float rs = rsqrtf(s2 * (1.f / 512.f) - mean * mean + 1e-5f);
  float g[8], bb[8];
  *(float4*)&g[0] = *(const float4*)(G + l * 8);
  *(float4*)&g[4] = *(const float4*)(G + l * 8 + 4);
  *(float4*)&bb[0] = *(const float4*)(B + l * 8);
  *(float4*)&bb[4] = *(const float4*)(B + l * 8 + 4);
  u16x8 o8;
#pragma unroll
  for (int e = 0; e < 8; ++e) o8[e] = f2h((v[e] - mean) * rs * g[e] + bb[e]);
  *(u16x8*)(H + ((size_t)row << 9) + l * 8) = o8;
}

// ---------------- qkv GEMM (temporal): round-11 form, proven 80 VGPR ----------------
template <int K>
__global__ __launch_bounds__(256)
void gemm_qkv(const u16* __restrict__ A, const u16* __restrict__ Bt,
              u16* __restrict__ Cq, u16* __restrict__ Cv, int lda, int ldb) {
  __shared__ u16 lds[2 * 128 * 64];  // lsA | lsB; reused as epilogue bounce [64][136]
  u16* lsA = lds;
  u16* lsB = lds + 128 * 64;
  const int tid = threadIdx.x;
  const int w = tid >> 6, l = tid & 63;
  const int lr = l & 15, lg = l >> 4;
  const int wm = w >> 1, wn = w & 1;
  const int gx = gridDim.x;
  const int wk = xcd_remap(blockIdx.y * gx + blockIdx.x, gx * gridDim.y);
  const int Row0 = (wk / gx) * 128, Col0 = (wk % gx) * 128;
  const int gcol = ((l & 7) ^ (l >> 3)) * 8;

  const int srow = w * 32 + (l >> 3);
  const u16* baseA = A + (size_t)(Row0 + srow) * lda + gcol;
  const u16* baseB = Bt + (size_t)(Col0 + srow) * ldb + gcol;

  f32x4 acc[4][4];
  const f32x4 zero = {0.f, 0.f, 0.f, 0.f};
#pragma unroll
  for (int m = 0; m < 4; ++m)
#pragma unroll
    for (int n = 0; n < 4; ++n) acc[m][n] = zero;

#pragma unroll
  for (int k0 = 0; k0 < K; k0 += 64) {
    __syncthreads();
#pragma unroll
    for (int i = 0; i < 4; ++i) {
      gl2lds16(baseA + (size_t)(i * 8) * lda + k0, &lsA[w * 2048 + i * 512]);
      gl2lds16(baseB + (size_t)(i * 8) * ldb + k0, &lsB[w * 2048 + i * 512]);
    }
    __syncthreads();
#pragma unroll
    for (int kk = 0; kk < 64; kk += 32) {
      f16x8 af[4], bfv[4];
#pragma unroll
      for (int m = 0; m < 4; ++m)
        af[m] = ldf16(&lsA[swz(wm * 64 + m * 16 + lr, kk + 8 * lg)]);
#pragma unroll
      for (int n = 0; n < 4; ++n)
        bfv[n] = ldf16(&lsB[swz(wn * 64 + n * 16 + lr, kk + 8 * lg)]);
#pragma unroll
      for (int m = 0; m < 4; ++m)
#pragma unroll
        for (int n = 0; n < 4; ++n) acc[m][n] = mfma_f16(af[m], bfv[n], acc[m][n]);
    }
  }

  const bool isV = (Col0 >= 1024);
#pragma unroll
  for (int p = 0; p < 2; ++p) {
    __syncthreads();
    if (wm == p) {
#pragma unroll
      for (int m = 0; m < 4; ++m)
#pragma unroll
        for (int n = 0; n < 4; ++n) {
          int col = wn * 64 + n * 16 + lr;
#pragma unroll
          for (int r = 0; r < 4; ++r)
            lds[(m * 16 + lg * 4 + r) * 136 + col] = f2h(acc[m][n][r]);
        }
    }
    __syncthreads();
#pragma unroll
    for (int it = 0; it < 4; ++it) {
      int cid = it * 256 + tid;
      int rl = cid >> 4, cc = (cid & 15) * 8;
      u16x8 vv = *(u16x8*)&lds[rl * 136 + cc];
      int gr = Row0 + p * 64 + rl;
      int gc = Col0 + cc;
      if (!isV)
        *(u16x8*)&Cq[(size_t)gr * 1024 + gc] = vv;
      else
        *(u16x8*)&Cv[(size_t)gr * 512 + gc - 1024] = vv;
    }
  }
}

// ---------------- spatial Q|K GEMM: cols 0..1023 only, single straight epilogue ----------
template <int K>
__global__ __launch_bounds__(256)
void gemm_qk_s(const u16* __restrict__ A, const u16* __restrict__ Bt,
               u16* __restrict__ Cq, int lda, int ldb) {
  __shared__ u16 lds[2 * 128 * 64];
  u16* lsA = lds;
  u16* lsB = lds + 128 * 64;
  const int tid = threadIdx.x;
  const int w = tid >> 6, l = tid & 63;
  const int lr = l & 15, lg = l >> 4;
  const int wm = w >> 1, wn = w & 1;
  const int gx = gridDim.x;
  const int wk = xcd_remap(blockIdx.y * gx + blockIdx.x, gx * gridDim.y);
  const int Row0 = (wk / gx) * 128, Col0 = (wk % gx) * 128;
  const int gcol = ((l & 7) ^ (l >> 3)) * 8;

  const int srow = w * 32 + (l >> 3);
  const u16* baseA = A + (size_t)(Row0 + srow) * lda + gcol;
  const u16* baseB = Bt + (size_t)(Col0 + srow) * ldb + gcol;

  f32x4 acc[4][4];
  const f32x4 zero = {0.f, 0.f, 0.f, 0.f};
#pragma unroll
  for (int m = 0; m < 4; ++m)
#pragma unroll
    for (int n = 0; n < 4; ++n) acc[m][n] = zero;

#pragma unroll
  for (int k0 = 0; k0 < K; k0 += 64) {
    __syncthreads();
#pragma unroll
    for (int i = 0; i < 4; ++i) {
      gl2lds16(baseA + (size_t)(i * 8) * lda + k0, &lsA[w * 2048 + i * 512]);
      gl2lds16(baseB + (size_t)(i * 8) * ldb + k0, &lsB[w * 2048 + i * 512]);
    }
    __syncthreads();
#pragma unroll
    for (int kk = 0; kk < 64; kk += 32) {
      f16x8 af[4], bfv[4];
#pragma unroll
      for (int m = 0; m < 4; ++m)
        af[m] = ldf16(&lsA[swz(wm * 64 + m * 16 + lr, kk + 8 * lg)]);
#pragma unroll
      for (int n = 0; n < 4; ++n)
        bfv[n] = ldf16(&lsB[swz(wn * 64 + n * 16 + lr, kk + 8 * lg)]);
#pragma unroll
      for (int m = 0; m < 4; ++m)
#pragma unroll
        for (int n = 0; n < 4; ++n) acc[m][n] = mfma_f16(af[m], bfv[n], acc[m][n]);
    }
  }

#pragma unroll
  for (int p = 0; p < 2; ++p) {
    __syncthreads();
    if (wm == p) {
#pragma unroll
      for (int m = 0; m < 4; ++m)
#pragma unroll
        for (int n = 0; n < 4; ++n) {
          int col = wn * 64 + n * 16 + lr;
#pragma unroll
          for (int r = 0; r < 4; ++r)
            lds[(m * 16 + lg * 4 + r) * 136 + col] = f2h(acc[m][n][r]);
        }
    }
    __syncthreads();
#pragma unroll
    for (int it = 0; it < 4; ++it) {
      int cid = it * 256 + tid;
      int rl = cid >> 4, cc = (cid & 15) * 8;
      u16x8 vv = *(u16x8*)&lds[rl * 136 + cc];
      *(u16x8*)&Cq[(size_t)(Row0 + p * 64 + rl) * 1024 + Col0 + cc] = vv;
    }
  }
}

// ---------------- spatial V GEMM: V weight block only, TRANSPOSED epilogue ----------
// Bt pre-offset to V rows. Col0 = d0 in [0,512). Output Vt[bt][d][c].
template <int K>
__global__ __launch_bounds__(256)
void gemm_vt_s(const u16* __restrict__ A, const u16* __restrict__ Bt,
               u16* __restrict__ Vt, int lda, int ldb) {
  __shared__ u16 lds[2 * 128 * 64];
  u16* lsA = lds;
  u16* lsB = lds + 128 * 64;
  const int tid = threadIdx.x;
  const int w = tid >> 6, l = tid & 63;
  const int lr = l & 15, lg = l >> 4;
  const int wm = w >> 1, wn = w & 1;
  const int gx = gridDim.x;
  const int wk = xcd_remap(blockIdx.y * gx + blockIdx.x, gx * gridDim.y);
  const int Row0 = (wk / gx) * 128, Col0 = (wk % gx) * 128;
  const int gcol = ((l & 7) ^ (l >> 3)) * 8;

  const int srow = w * 32 + (l >> 3);
  const u16* baseA = A + (size_t)(Row0 + srow) * lda + gcol;
  const u16* baseB = Bt + (size_t)(Col0 + srow) * ldb + gcol;

  f32x4 acc[4][4];
  const f32x4 zero = {0.f, 0.f, 0.f, 0.f};
#pragma unroll
  for (int m = 0; m < 4; ++m)
#pragma unroll
    for (int n = 0; n < 4; ++n) acc[m][n] = zero;

#pragma unroll
  for (int k0 = 0; k0 < K; k0 += 64) {
    __syncthreads();
#pragma unroll
    for (int i = 0; i < 4; ++i) {
      gl2lds16(baseA + (size_t)(i * 8) * lda + k0, &lsA[w * 2048 + i * 512]);
      gl2lds16(baseB + (size_t)(i * 8) * ldb + k0, &lsB[w * 2048 + i * 512]);
    }
    __syncthreads();
#pragma unroll
    for (int kk = 0; kk < 64; kk += 32) {
      f16x8 af[4], bfv[4];
#pragma unroll
      for (int m = 0; m < 4; ++m)
        af[m] = ldf16(&lsA[swz(wm * 64 + m * 16 + lr, kk + 8 * lg)]);
#pragma unroll
      for (int n = 0; n < 4; ++n)
        bfv[n] = ldf16(&lsB[swz(wn * 64 + n * 16 + lr, kk + 8 * lg)]);
#pragma unroll
      for (int m = 0; m < 4; ++m)
#pragma unroll
        for (int n = 0; n < 4; ++n) acc[m][n] = mfma_f16(af[m], bfv[n], acc[m][n]);
    }
  }

  // transposed epilogue: tile = c [Row0&1023,+128) x d [Col0,+128); Vt[bt][d][c]
  const int bt = Row0 >> 10;
  const int c0 = Row0 & 1023;
  const int d0 = Col0;
#pragma unroll
  for (int p = 0; p < 2; ++p) {
    __syncthreads();
    if (wm == p) {
#pragma unroll
      for (int m = 0; m < 4; ++m)
#pragma unroll
        for (int n = 0; n < 4; ++n) {
          int col = wn * 64 + n * 16 + lr;  // d_local
#pragma unroll
          for (int r = 0; r < 4; ++r)
            lds[col * 72 + m * 16 + lg * 4 + r] = f2h(acc[m][n][r]);  // [d][c] pad 72
        }
    }
    __syncthreads();
#pragma unroll
    for (int it = 0; it < 4; ++it) {
      int cid = it * 256 + tid;
      int dl = cid >> 3, cc = (cid & 7) * 8;
      u16x8 vv = *(u16x8*)&lds[dl * 72 + cc];
      *(u16x8*)&Vt[(size_t)bt * 524288 + (size_t)(d0 + dl) * 1024 + c0 + p * 64 + cc] = vv;
    }
  }
}

// ---------------- fp16 GEMM 128x128xK (unrolled), A[M,K], B^T[N,K], batched ----------------
// REMAP: 0 none, 1 = 2D XCD remap, 2 = 3D flatten+XCD remap (batched ops).
template <bool OUT16, int REMAP, int K>
__global__ __launch_bounds__(256)
void gemm_bt(const u16* __restrict__ A, const u16* __restrict__ Bt,
             void* __restrict__ Cp, const float* __restrict__ bias,
             int lda, int ldb, int ldc,
             long long sA, long long sB, long long sC, float scale) {
  __shared__ u16 lds[2 * 128 * 64];
  u16* lsA = lds;
  u16* lsB = lds + 128 * 64;
  const int tid = threadIdx.x;
  const int w = tid >> 6, l = tid & 63;
  const int lr = l & 15, lg = l >> 4;
  const int wm = w >> 1, wn = w & 1;
  int Row0, Col0, bz;
  if constexpr (REMAP == 1) {
    const int gx = gridDim.x;
    const int wk = xcd_remap(blockIdx.y * gx + blockIdx.x, gx * gridDim.y);
    Row0 = (wk / gx) * 128; Col0 = (wk % gx) * 128; bz = blockIdx.z;
  } else if constexpr (REMAP == 2) {
    const int gx = gridDim.x, gy = gridDim.y;
    const int d = blockIdx.x + gx * (blockIdx.y + gy * blockIdx.z);
    const int wk = xcd_remap(d, gx * gy * gridDim.z);
    Col0 = (wk % gx) * 128;
    int rest = wk / gx;
    Row0 = (rest % gy) * 128;
    bz = rest / gy;
  } else {
    Row0 = blockIdx.y * 128; Col0 = blockIdx.x * 128; bz = blockIdx.z;
  }
  const int gcol = ((l & 7) ^ (l >> 3)) * 8;

  const int srow = w * 32 + (l >> 3);
  const u16* baseA = A + (size_t)bz * sA + (size_t)(Row0 + srow) * lda + gcol;
  const u16* baseB = Bt + (size_t)bz * sB + (size_t)(Col0 + srow) * ldb + gcol;

  f32x4 acc[4][4];
  const f32x4 zero = {0.f, 0.f, 0.f, 0.f};
#pragma unroll
  for (int m = 0; m < 4; ++m)
#pragma unroll
    for (int n = 0; n < 4; ++n) acc[m][n] = zero;

#pragma unroll
  for (int k0 = 0; k0 < K; k0 += 64) {
    __syncthreads();
#pragma unroll
    for (int i = 0; i < 4; ++i) {
      gl2lds16(baseA + (size_t)(i * 8) * lda + k0, &lsA[w * 2048 + i * 512]);
      gl2lds16(baseB + (size_t)(i * 8) * ldb + k0, &lsB[w * 2048 + i * 512]);
    }
    __syncthreads();
#pragma unroll
    for (int kk = 0; kk < 64; kk += 32) {
      f16x8 af[4], bfv[4];
#pragma unroll
      for (int m = 0; m < 4; ++m)
        af[m] = ldf16(&lsA[swz(wm * 64 + m * 16 + lr, kk + 8 * lg)]);
#pragma unroll
      for (int n = 0; n < 4; ++n)
        bfv[n] = ldf16(&lsB[swz(wn * 64 + n * 16 + lr, kk + 8 * lg)]);
#pragma unroll
      for (int m = 0; m < 4; ++m)
#pragma unroll
        for (int n = 0; n < 4; ++n) acc[m][n] = mfma_f16(af[m], bfv[n], acc[m][n]);
    }
  }

  if constexpr (OUT16) {
    u16* Cb = (u16*)Cp + (size_t)bz * sC;
#pragma unroll
    for (int p = 0; p < 2; ++p) {
      __syncthreads();
      if (wm == p) {
#pragma unroll
        for (int m = 0; m < 4; ++m)
#pragma unroll
          for (int n = 0; n < 4; ++n) {
            int col = wn * 64 + n * 16 + lr;
            float bv = bias ? bias[Col0 + col] : 0.f;
#pragma unroll
            for (int r = 0; r < 4; ++r)
              lds[(m * 16 + lg * 4 + r) * 136 + col] = f2h(acc[m][n][r] * scale + bv);
          }
      }
      __syncthreads();
#pragma unroll
      for (int it = 0; it < 4; ++it) {
        int cid = it * 256 + tid;
        int rl = cid >> 4, cc = (cid & 15) * 8;
        u16x8 vv = *(u16x8*)&lds[rl * 136 + cc];
        *(u16x8*)&Cb[(size_t)(Row0 + p * 64 + rl) * ldc + Col0 + cc] = vv;
      }
    }
  } else {
    float* Cb = (float*)Cp + (size_t)bz * sC;
    float* ldsF = (float*)lds;  // [32][132] fp32
#pragma unroll
    for (int q = 0; q < 4; ++q) {
      __syncthreads();
      if (wm == (q >> 1)) {
        int mBase = (q & 1) * 2;
#pragma unroll
        for (int mi = 0; mi < 2; ++mi) {
          int m = mBase + mi;
#pragma unroll
          for (int n = 0; n < 4; ++n) {
            int col = wn * 64 + n * 16 + lr;
            float bv = bias ? bias[Col0 + col] : 0.f;
#pragma unroll
            for (int r = 0; r < 4; ++r)
              ldsF[(mi * 16 + lg * 4 + r) * 132 + col] = acc[m][n][r] * scale + bv;
          }
        }
      }
      __syncthreads();
#pragma unroll
      for (int it = 0; it < 4; ++it) {
        int cid = it * 256 + tid;
        int rw = cid >> 5, c4 = (cid & 31) * 4;
        float4 v = *(float4*)&ldsF[rw * 132 + c4];
        *(float4*)&Cb[(size_t)(Row0 + q * 32 + rw) * ldc + Col0 + c4] = v;
      }
    }
  }
}

// ---------------- fused temporal attention (fp16), one block per (b,c) ----------------
__global__ __launch_bounds__(256)
void attn_t_kernel(const u16* __restrict__ QK, const u16* __restrict__ Vb,
                   u16* __restrict__ O) {
  __shared__ u16 qs[32 * 520];
  __shared__ u16 ks[32 * 520];
  __shared__ u16 vT[512 * 40];
  __shared__ float Sf[32 * 36];
  __shared__ u16 Pf[32 * 40];

  const int tid = threadIdx.x;
  const int bc = blockIdx.x;  // b*1024 + c
  const int w = tid >> 6, l = tid & 63, lr = l & 15, lg = l >> 4;
  const int wr = w >> 1, wc = w & 1;
  const size_t base = (size_t)(bc >> 10) * 32768 + (bc & 1023);

#pragma unroll
  for (int i = 0; i < 8; ++i) {
    int t = w * 8 + i;
    const u16* rb = QK + (base + (size_t)t * 1024) * 1024;
    gl2lds16(rb + l * 8, &qs[t * 520]);
    gl2lds16(rb + 512 + l * 8, &ks[t * 520]);
  }
  {  // V staging, t-major lanes: conflict-free vT writes
    const int t = tid & 31;
    const int db0 = (tid >> 5) * 8;
    const u16* vrow = Vb + (base + (size_t)t * 1024) * 512;
#pragma unroll
    for (int j = 0; j < 8; ++j) {
      int db = db0 + j;
      u16x8 vv = *(const u16x8*)(vrow + db * 8);
#pragma unroll
      for (int e = 0; e < 8; ++e) vT[(db * 8 + e) * 40 + t] = vv[e];
    }
  }
  __syncthreads();

  f32x4 sacc = {0.f, 0.f, 0.f, 0.f};
#pragma unroll
  for (int kk = 0; kk < 512; kk += 32)
    sacc = mfma_f16(ldf16(&qs[(wr * 16 + lr) * 520 + kk + 8 * lg]),
                    ldf16(&ks[(wc * 16 + lr) * 520 + kk + 8 * lg]), sacc);
#pragma unroll
  for (int r = 0; r < 4; ++r)
    Sf[(wr * 16 + lg * 4 + r) * 36 + wc * 16 + lr] = sacc[r] * 0.125f;
  __syncthreads();

  {  // parallel softmax: 8 threads per row
    const int row = tid >> 3, c0 = (tid & 7) * 4;
    float4 sv = *(float4*)&Sf[row * 36 + c0];
    float mx = fmaxf(fmaxf(sv.x, sv.y), fmaxf(sv.z, sv.w));
#pragma unroll
    for (int o = 1; o < 8; o <<= 1) mx = fmaxf(mx, __shfl_xor(mx, o, 64));
    float e0 = __expf(sv.x - mx), e1 = __expf(sv.y - mx);
    float e2 = __expf(sv.z - mx), e3 = __expf(sv.w - mx);
    float sum = e0 + e1 + e2 + e3;
#pragma unroll
    for (int o = 1; o < 8; o <<= 1) sum += __shfl_xor(sum, o, 64);
    float inv = 1.f / sum;
    u16x4 p4 = {f2h(e0 * inv), f2h(e1 * inv), f2h(e2 * inv), f2h(e3 * inv)};
    *(u16x4*)&Pf[row * 40 + c0] = p4;
  }
  __syncthreads();

  {  // O = P @ V, staged into qs for coalesced u16x8 stores
    const int mr = w >> 1, nh = w & 1;
    f16x8 ap = ldf16(&Pf[(mr * 16 + lr) * 40 + 8 * lg]);
#pragma unroll
    for (int j = 0; j < 16; ++j) {
      int nc = (nh * 16 + j) * 16;
      f32x4 o = {0.f, 0.f, 0.f, 0.f};
      o = mfma_f16(ap, ldf16(&vT[(nc + lr) * 40 + 8 * lg]), o);
#pragma unroll
      for (int r = 0; r < 4; ++r)
        qs[(mr * 16 + lg * 4 + r) * 520 + nc + lr] = f2h(o[r]);
    }
  }
  __syncthreads();
#pragma unroll
  for (int it = 0; it < 8; ++it) {
    int cid = it * 256 + tid;
    int t = cid >> 6, col = (cid & 63) * 8;
    u16x8 vv = *(u16x8*)&qs[t * 520 + col];
    *(u16x8*)&O[(base + (size_t)t * 1024) * 512 + col] = vv;
  }
}

// ---------------- row softmax over 1024 fp16, in place ----------------
__global__ __launch_bounds__(256)
void softmax16_kernel(u16* __restrict__ S) {
  u16* p = S + ((size_t)blockIdx.x << 10);
  const int tid = threadIdx.x, w = tid >> 6, l = tid & 63;
  __shared__ float red[8];
  u16x4 raw = *(u16x4*)&p[tid << 2];
  float v0 = h2f(raw[0]), v1 = h2f(raw[1]), v2 = h2f(raw[2]), v3 = h2f(raw[3]);
  float m = fmaxf(fmaxf(v0, v1), fmaxf(v2, v3));
#pragma unroll
  for (int o = 1; o < 64; o <<= 1) m = fmaxf(m, __shfl_xor(m, o, 64));
  if (l == 0) red[w] = m;
  __syncthreads();
  m = fmaxf(fmaxf(red[0], red[1]), fmaxf(red[2], red[3]));
  v0 = __expf(v0 - m); v1 = __expf(v1 - m); v2 = __expf(v2 - m); v3 = __expf(v3 - m);
  float s = v0 + v1 + v2 + v3;
#pragma unroll
  for (int o = 1; o < 64; o <<= 1) s += __shfl_xor(s, o, 64);
  if (l == 0) red[4 + w] = s;
  __syncthreads();
  const float inv = 1.f / (red[4] + red[5] + red[6] + red[7]);
  u16x4 o4 = {f2h(v0 * inv), f2h(v1 * inv), f2h(v2 * inv), f2h(v3 * inv)};
  *(u16x4*)&p[tid << 2] = o4;
}

extern "C" void kernel_launch(void* const* d_in, const int* in_sizes, int n_in,
                              void* d_out, int out_size, void* d_ws, size_t ws_size,
                              hipStream_t stream) {
  (void)in_sizes; (void)n_in; (void)out_size; (void)ws_size;
  const float* x      = (const float*)d_in[0];
  const float* gam_t  = (const float*)d_in[1];
  const float* bet_t  = (const float*)d_in[2];
  const float* wqkv_t = (const float*)d_in[3];
  const float* wout_t = (const float*)d_in[4];
  const float* bout_t = (const float*)d_in[5];
  const float* gam_s  = (const float*)d_in[6];
  const float* bet_s  = (const float*)d_in[7];
  const float* wqkv_s = (const float*)d_in[8];
  const float* wout_s = (const float*)d_in[9];
  const float* bout_s = (const float*)d_in[10];
  float* out = (float*)d_out;

  char* ws = (char*)d_ws;
  size_t off = 0;
  auto alloc = [&](size_t bytes) -> char* {
    char* p = ws + off;
    off = (off + bytes + 255) & ~(size_t)255;
    return p;
  };
  // Total ~392 MiB (< 424 proven). Aliases: h = S region; out1 = QK first half; Vt = Vb slot.
  u16* wqkvT_t = (u16*)alloc((size_t)1536 * 512 * 2);
  u16* woutT_t = (u16*)alloc((size_t)512 * 512 * 2);
  u16* wqkvT_s = (u16*)alloc((size_t)1536 * 512 * 2);
  u16* woutT_s = (u16*)alloc((size_t)512 * 512 * 2);
  u16* QK      = (u16*)alloc((size_t)65536 * 1024 * 2);      // 128 MiB
  u16* Vb      = (u16*)alloc((size_t)65536 * 512 * 2);       //  64 MiB (temporal V / spatial Vt)
  u16* attnO   = (u16*)alloc((size_t)65536 * 512 * 2);       //  64 MiB
  u16* S       = (u16*)alloc((size_t)64 * 1024 * 1024 * 2);  // 128 MiB (single pass)
  u16* h       = S;    // LN output (64 MiB), dead before S is written
  u16* out1    = QK;   // temporal block output fp16 (64 MiB)
  u16* Vt      = Vb;   // spatial V transposed [bt][512][1024]

  const dim3 blk(256);

  wT_all_kernel<<<2048, blk, 0, stream>>>(wqkv_t, wout_t, wqkv_s, wout_s,
                                          wqkvT_t, woutT_t, wqkvT_s, woutT_s);

  // ---- temporal ----
  ln_kernel<<<16384, blk, 0, stream>>>(x, gam_t, bet_t, h);
  gemm_qkv<512><<<dim3(12, 512, 1), blk, 0, stream>>>(h, wqkvT_t, QK, Vb, 512, 512);
  attn_t_kernel<<<2048, blk, 0, stream>>>(QK, Vb, attnO);
  gemm_bt<true, 1, 512><<<dim3(4, 512, 1), blk, 0, stream>>>(
      attnO, woutT_t, out1, bout_t, 512, 512, 512, 0, 0, 0, 1.f);

  // ---- spatial (Q|K straight; V transposed by dedicated kernel; single chunk) ----
  ln16_kernel<<<16384, blk, 0, stream>>>(out1, gam_s, bet_s, h);
  gemm_qk_s<512><<<dim3(8, 512, 1), blk, 0, stream>>>(h, wqkvT_s, QK, 512, 512);
  gemm_vt_s<512><<<dim3(4, 512, 1), blk, 0, stream>>>(
      h, wqkvT_s + (size_t)1024 * 512, Vt, 512, 512);

  gemm_bt<true, 2, 512><<<dim3(8, 8, 64), blk, 0, stream>>>(
      QK, QK + 512, S, nullptr, 1024, 1024, 1024,
      1024LL * 1024, 1024LL * 1024, 1024LL * 1024, 0.125f);
  softmax16_kernel<<<65536, blk, 0, stream>>>(S);
  gemm_bt<true, 2, 1024><<<dim3(4, 8, 64), blk, 0, stream>>>(
      S, Vt, attnO, nullptr, 1024, 1024, 512,
      1024LL * 1024, 512LL * 1024, 1024LL * 512, 1.f);

  gemm_bt<false, 1, 512><<<dim3(4, 512, 1), blk, 0, stream>>>(
      attnO, woutT_s, out, bout_s, 512, 512, 512, 0, 0, 0, 1.f);
}

// Round 17
// 782.779 us; speedup vs baseline: 1.0692x; 1.0200x over previous
//
#include <hip/hip_runtime.h>
#include <type_traits>

typedef unsigned short u16;
typedef _Float16 f16;
typedef f16 f16x8 __attribute__((ext_vector_type(8)));
typedef unsigned short u16x8 __attribute__((ext_vector_type(8)));
typedef unsigned short u16x4 __attribute__((ext_vector_type(4)));
typedef float f32x4 __attribute__((ext_vector_type(4)));

#define DEV __device__ __forceinline__

DEV u16 f2h(float f) { return __builtin_bit_cast(u16, (f16)f); }  // RNE
DEV float h2f(u16 u) { return (float)__builtin_bit_cast(f16, u); }

DEV f32x4 mfma_f16(f16x8 a, f16x8 b, f32x4 c) {
  return __builtin_amdgcn_mfma_f32_16x16x32_f16(a, b, c, 0, 0, 0);
}
DEV f16x8 ldf16(const u16* p) { return *(const f16x8*)p; }

DEV void gl2lds16(const u16* g, u16* l) {
  __builtin_amdgcn_global_load_lds((const __attribute__((address_space(1))) void*)g,
                                   (__attribute__((address_space(3))) void*)l, 16, 0, 0);
}

// LDS tile [rows][64 u16], XOR-swizzled: physical col = col ^ ((row&7)<<3).
DEV int swz(int row, int col) { return row * 64 + (col ^ ((row & 7) << 3)); }

// XCD-chunked remap (nwg % 8 == 0): each XCD owns a contiguous work chunk.
DEV int xcd_remap(int d, int nwg) { return (d & 7) * (nwg >> 3) + (d >> 3); }

// ---------------- all four weights: transpose fp32 -> fp16, 8 els/thread ----------------
__global__ __launch_bounds__(256)
void wT_all_kernel(const float* __restrict__ Wq_t, const float* __restrict__ Wo_t,
                   const float* __restrict__ Wq_s, const float* __restrict__ Wo_s,
                   u16* __restrict__ Tq_t, u16* __restrict__ To_t,
                   u16* __restrict__ Tq_s, u16* __restrict__ To_s) {
  const int bid = blockIdx.x;
  const float* W;
  u16* T;
  int N, base;
  if (bid < 384)      { W = Wq_t; T = Tq_t; N = 1536; base = bid; }
  else if (bid < 512) { W = Wo_t; T = To_t; N = 512;  base = bid - 384; }
  else if (bid < 896) { W = Wq_s; T = Tq_s; N = 1536; base = bid - 512; }
  else                { W = Wo_s; T = To_s; N = 512;  base = bid - 896; }
#pragma unroll
  for (int j = 0; j < 8; ++j) {
    int i = base * 2048 + j * 256 + threadIdx.x;
    int n = i >> 9, k = i & 511;
    T[i] = f2h(W[(size_t)k * N + n]);
  }
}

// ---------------- fused LayerNorm (rows of 512 fp32) -> fp16 ----------------
__global__ __launch_bounds__(256)
void ln_kernel(const float* __restrict__ X, const float* __restrict__ G,
               const float* __restrict__ B, u16* __restrict__ H) {
  const int row = (blockIdx.x << 2) + (threadIdx.x >> 6);
  const int l = threadIdx.x & 63;
  const float* x = X + ((size_t)row << 9) + l * 8;
  float v[8];
  *(float4*)&v[0] = *(const float4*)(x);
  *(float4*)&v[4] = *(const float4*)(x + 4);
  float s = 0.f, s2 = 0.f;
#pragma unroll
  for (int e = 0; e < 8; ++e) { s += v[e]; s2 += v[e] * v[e]; }
#pragma unroll
  for (int o = 1; o < 64; o <<= 1) { s += __shfl_xor(s, o, 64); s2 += __shfl_xor(s2, o, 64); }
  const float mean = s * (1.f / 512.f);
  const float rs = rsqrtf(s2 * (1.f / 512.f) - mean * mean + 1e-5f);
  float g[8], bb[8];
  *(float4*)&g[0] = *(const float4*)(G + l * 8);
  *(float4*)&g[4] = *(const float4*)(G + l * 8 + 4);
  *(float4*)&bb[0] = *(const float4*)(B + l * 8);
  *(float4*)&bb[4] = *(const float4*)(B + l * 8 + 4);
  u16x8 o8;
#pragma unroll
  for (int e = 0; e < 8; ++e) o8[e] = f2h((v[e] - mean) * rs * g[e] + bb[e]);
  *(u16x8*)(H + ((size_t)row << 9) + l * 8) = o8;
}

// ---------------- LayerNorm on fp16 rows of 512 -> fp16 ----------------
__global__ __launch_bounds__(256)
void ln16_kernel(const u16* __restrict__ X, const float* __restrict__ G,
                 const float* __restrict__ B, u16* __restrict__ H) {
  const int row = (blockIdx.x << 2) + (threadIdx.x >> 6);
  const int l = threadIdx.x & 63;
  u16x8 raw = *(const u16x8*)(X + ((size_t)row << 9) + l * 8);
  float v[8];
#pragma unroll
  for (int e = 0; e < 8; ++e) v[e] = h2f(raw[e]);
  float s = 0.f, s2 = 0.f;
#pragma unroll
  for (int e = 0; e < 8; ++e) { s += v[e]; s2 += v[e] * v[e]; }
#pragma unroll
  for (int o = 1; o < 64; o <<= 1) { s += __shfl_xor(s, o, 64); s2 += __shfl_xor(s2, o, 64); }
  const float mean = s * (1.f / 512.f);
  const float rs = rsqrtf(s2 * (1.f / 512.f) - mean * mean + 1e-5f);
  float g[8], bb[8];
  *(float4*)&g[0] = *(const float4*)(G + l * 8);
  *(float4*)&g[4] = *(const float4*)(G + l * 8 + 4);
  *(float4*)&bb[0] = *(const float4*)(B + l * 8);
  *(float4*)&bb[4] = *(const float4*)(B + l * 8 + 4);
  u16x8 o8;
#pragma unroll
  for (int e = 0; e < 8; ++e) o8[e] = f2h((v[e] - mean) * rs * g[e] + bb[e]);
  *(u16x8*)(H + ((size_t)row << 9) + l * 8) = o8;
}

// ---------------- qkv GEMM (temporal): round-11 form, proven 80 VGPR ----------------
template <int K>
__global__ __launch_bounds__(256)
void gemm_qkv(const u16* __restrict__ A, const u16* __restrict__ Bt,
              u16* __restrict__ Cq, u16* __restrict__ Cv, int lda, int ldb) {
  __shared__ u16 lds[2 * 128 * 64];  // lsA | lsB; reused as epilogue bounce [64][136]
  u16* lsA = lds;
  u16* lsB = lds + 128 * 64;
  const int tid = threadIdx.x;
  const int w = tid >> 6, l = tid & 63;
  const int lr = l & 15, lg = l >> 4;
  const int wm = w >> 1, wn = w & 1;
  const int gx = gridDim.x;
  const int wk = xcd_remap(blockIdx.y * gx + blockIdx.x, gx * gridDim.y);
  const int Row0 = (wk / gx) * 128, Col0 = (wk % gx) * 128;
  const int gcol = ((l & 7) ^ (l >> 3)) * 8;

  const int srow = w * 32 + (l >> 3);
  const u16* baseA = A + (size_t)(Row0 + srow) * lda + gcol;
  const u16* baseB = Bt + (size_t)(Col0 + srow) * ldb + gcol;

  f32x4 acc[4][4];
  const f32x4 zero = {0.f, 0.f, 0.f, 0.f};
#pragma unroll
  for (int m = 0; m < 4; ++m)
#pragma unroll
    for (int n = 0; n < 4; ++n) acc[m][n] = zero;

#pragma unroll
  for (int k0 = 0; k0 < K; k0 += 64) {
    __syncthreads();
#pragma unroll
    for (int i = 0; i < 4; ++i) {
      gl2lds16(baseA + (size_t)(i * 8) * lda + k0, &lsA[w * 2048 + i * 512]);
      gl2lds16(baseB + (size_t)(i * 8) * ldb + k0, &lsB[w * 2048 + i * 512]);
    }
    __syncthreads();
#pragma unroll
    for (int kk = 0; kk < 64; kk += 32) {
      f16x8 af[4], bfv[4];
#pragma unroll
      for (int m = 0; m < 4; ++m)
        af[m] = ldf16(&lsA[swz(wm * 64 + m * 16 + lr, kk + 8 * lg)]);
#pragma unroll
      for (int n = 0; n < 4; ++n)
        bfv[n] = ldf16(&lsB[swz(wn * 64 + n * 16 + lr, kk + 8 * lg)]);
#pragma unroll
      for (int m = 0; m < 4; ++m)
#pragma unroll
        for (int n = 0; n < 4; ++n) acc[m][n] = mfma_f16(af[m], bfv[n], acc[m][n]);
    }
  }

  const bool isV = (Col0 >= 1024);
#pragma unroll
  for (int p = 0; p < 2; ++p) {
    __syncthreads();
    if (wm == p) {
#pragma unroll
      for (int m = 0; m < 4; ++m)
#pragma unroll
        for (int n = 0; n < 4; ++n) {
          int col = wn * 64 + n * 16 + lr;
#pragma unroll
          for (int r = 0; r < 4; ++r)
            lds[(m * 16 + lg * 4 + r) * 136 + col] = f2h(acc[m][n][r]);
        }
    }
    __syncthreads();
#pragma unroll
    for (int it = 0; it < 4; ++it) {
      int cid = it * 256 + tid;
      int rl = cid >> 4, cc = (cid & 15) * 8;
      u16x8 vv = *(u16x8*)&lds[rl * 136 + cc];
      int gr = Row0 + p * 64 + rl;
      int gc = Col0 + cc;
      if (!isV)
        *(u16x8*)&Cq[(size_t)gr * 1024 + gc] = vv;
      else
        *(u16x8*)&Cv[(size_t)gr * 512 + gc - 1024] = vv;
    }
  }
}

// ---------------- spatial Q|K GEMM: cols 0..1023 only, single straight epilogue ----------
template <int K>
__global__ __launch_bounds__(256)
void gemm_qk_s(const u16* __restrict__ A, const u16* __restrict__ Bt,
               u16* __restrict__ Cq, int lda, int ldb) {
  __shared__ u16 lds[2 * 128 * 64];
  u16* lsA = lds;
  u16* lsB = lds + 128 * 64;
  const int tid = threadIdx.x;
  const int w = tid >> 6, l = tid & 63;
  const int lr = l & 15, lg = l >> 4;
  const int wm = w >> 1, wn = w & 1;
  const int gx = gridDim.x;
  const int wk = xcd_remap(blockIdx.y * gx + blockIdx.x, gx * gridDim.y);
  const int Row0 = (wk / gx) * 128, Col0 = (wk % gx) * 128;
  const int gcol = ((l & 7) ^ (l >> 3)) * 8;

  const int srow = w * 32 + (l >> 3);
  const u16* baseA = A + (size_t)(Row0 + srow) * lda + gcol;
  const u16* baseB = Bt + (size_t)(Col0 + srow) * ldb + gcol;

  f32x4 acc[4][4];
  const f32x4 zero = {0.f, 0.f, 0.f, 0.f};
#pragma unroll
  for (int m = 0; m < 4; ++m)
#pragma unroll
    for (int n = 0; n < 4; ++n) acc[m][n] = zero;

#pragma unroll
  for (int k0 = 0; k0 < K; k0 += 64) {
    __syncthreads();
#pragma unroll
    for (int i = 0; i < 4; ++i) {
      gl2lds16(baseA + (size_t)(i * 8) * lda + k0, &lsA[w * 2048 + i * 512]);
      gl2lds16(baseB + (size_t)(i * 8) * ldb + k0, &lsB[w * 2048 + i * 512]);
    }
    __syncthreads();
#pragma unroll
    for (int kk = 0; kk < 64; kk += 32) {
      f16x8 af[4], bfv[4];
#pragma unroll
      for (int m = 0; m < 4; ++m)
        af[m] = ldf16(&lsA[swz(wm * 64 + m * 16 + lr, kk + 8 * lg)]);
#pragma unroll
      for (int n = 0; n < 4; ++n)
        bfv[n] = ldf16(&lsB[swz(wn * 64 + n * 16 + lr, kk + 8 * lg)]);
#pragma unroll
      for (int m = 0; m < 4; ++m)
#pragma unroll
        for (int n = 0; n < 4; ++n) acc[m][n] = mfma_f16(af[m], bfv[n], acc[m][n]);
    }
  }

#pragma unroll
  for (int p = 0; p < 2; ++p) {
    __syncthreads();
    if (wm == p) {
#pragma unroll
      for (int m = 0; m < 4; ++m)
#pragma unroll
        for (int n = 0; n < 4; ++n) {
          int col = wn * 64 + n * 16 + lr;
#pragma unroll
          for (int r = 0; r < 4; ++r)
            lds[(m * 16 + lg * 4 + r) * 136 + col] = f2h(acc[m][n][r]);
        }
    }
    __syncthreads();
#pragma unroll
    for (int it = 0; it < 4; ++it) {
      int cid = it * 256 + tid;
      int rl = cid >> 4, cc = (cid & 15) * 8;
      u16x8 vv = *(u16x8*)&lds[rl * 136 + cc];
      *(u16x8*)&Cq[(size_t)(Row0 + p * 64 + rl) * 1024 + Col0 + cc] = vv;
    }
  }
}

// ---------------- spatial V GEMM: V weight block only, TRANSPOSED epilogue ----------
// Bt pre-offset to V rows. Col0 = d0 in [0,512). Output Vt[bt][d][c].
template <int K>
__global__ __launch_bounds__(256)
void gemm_vt_s(const u16* __restrict__ A, const u16* __restrict__ Bt,
               u16* __restrict__ Vt, int lda, int ldb) {
  __shared__ u16 lds[2 * 128 * 64];
  u16* lsA = lds;
  u16* lsB = lds + 128 * 64;
  const int tid = threadIdx.x;
  const int w = tid >> 6, l = tid & 63;
  const int lr = l & 15, lg = l >> 4;
  const int wm = w >> 1, wn = w & 1;
  const int gx = gridDim.x;
  const int wk = xcd_remap(blockIdx.y * gx + blockIdx.x, gx * gridDim.y);
  const int Row0 = (wk / gx) * 128, Col0 = (wk % gx) * 128;
  const int gcol = ((l & 7) ^ (l >> 3)) * 8;

  const int srow = w * 32 + (l >> 3);
  const u16* baseA = A + (size_t)(Row0 + srow) * lda + gcol;
  const u16* baseB = Bt + (size_t)(Col0 + srow) * ldb + gcol;

  f32x4 acc[4][4];
  const f32x4 zero = {0.f, 0.f, 0.f, 0.f};
#pragma unroll
  for (int m = 0; m < 4; ++m)
#pragma unroll
    for (int n = 0; n < 4; ++n) acc[m][n] = zero;

#pragma unroll
  for (int k0 = 0; k0 < K; k0 += 64) {
    __syncthreads();
#pragma unroll
    for (int i = 0; i < 4; ++i) {
      gl2lds16(baseA + (size_t)(i * 8) * lda + k0, &lsA[w * 2048 + i * 512]);
      gl2lds16(baseB + (size_t)(i * 8) * ldb + k0, &lsB[w * 2048 + i * 512]);
    }
    __syncthreads();
#pragma unroll
    for (int kk = 0; kk < 64; kk += 32) {
      f16x8 af[4], bfv[4];
#pragma unroll
      for (int m = 0; m < 4; ++m)
        af[m] = ldf16(&lsA[swz(wm * 64 + m * 16 + lr, kk + 8 * lg)]);
#pragma unroll
      for (int n = 0; n < 4; ++n)
        bfv[n] = ldf16(&lsB[swz(wn * 64 + n * 16 + lr, kk + 8 * lg)]);
#pragma unroll
      for (int m = 0; m < 4; ++m)
#pragma unroll
        for (int n = 0; n < 4; ++n) acc[m][n] = mfma_f16(af[m], bfv[n], acc[m][n]);
    }
  }

  // transposed epilogue: tile = c [Row0&1023,+128) x d [Col0,+128); Vt[bt][d][c]
  const int bt = Row0 >> 10;
  const int c0 = Row0 & 1023;
  const int d0 = Col0;
#pragma unroll
  for (int p = 0; p < 2; ++p) {
    __syncthreads();
    if (wm == p) {
#pragma unroll
      for (int m = 0; m < 4; ++m)
#pragma unroll
        for (int n = 0; n < 4; ++n) {
          int col = wn * 64 + n * 16 + lr;  // d_local
#pragma unroll
          for (int r = 0; r < 4; ++r)
            lds[col * 72 + m * 16 + lg * 4 + r] = f2h(acc[m][n][r]);  // [d][c] pad 72
        }
    }
    __syncthreads();
#pragma unroll
    for (int it = 0; it < 4; ++it) {
      int cid = it * 256 + tid;
      int dl = cid >> 3, cc = (cid & 7) * 8;
      u16x8 vv = *(u16x8*)&lds[dl * 72 + cc];
      *(u16x8*)&Vt[(size_t)bt * 524288 + (size_t)(d0 + dl) * 1024 + c0 + p * 64 + cc] = vv;
    }
  }
}

// ---------------- fp16 GEMM 128x128xK (unrolled), A[M,K], B^T[N,K], batched ----------------
// REMAP: 0 none, 1 = 2D XCD remap, 2 = 3D flatten+XCD remap (batched ops).
template <bool OUT16, int REMAP, int K>
__global__ __launch_bounds__(256)
void gemm_bt(const u16* __restrict__ A, const u16* __restrict__ Bt,
             void* __restrict__ Cp, const float* __restrict__ bias,
             int lda, int ldb, int ldc,
             long long sA, long long sB, long long sC, float scale) {
  __shared__ u16 lds[2 * 128 * 64];
  u16* lsA = lds;
  u16* lsB = lds + 128 * 64;
  const int tid = threadIdx.x;
  const int w = tid >> 6, l = tid & 63;
  const int lr = l & 15, lg = l >> 4;
  const int wm = w >> 1, wn = w & 1;
  int Row0, Col0, bz;
  if constexpr (REMAP == 1) {
    const int gx = gridDim.x;
    const int wk = xcd_remap(blockIdx.y * gx + blockIdx.x, gx * gridDim.y);
    Row0 = (wk / gx) * 128; Col0 = (wk % gx) * 128; bz = blockIdx.z;
  } else if constexpr (REMAP == 2) {
    const int gx = gridDim.x, gy = gridDim.y;
    const int d = blockIdx.x + gx * (blockIdx.y + gy * blockIdx.z);
    const int wk = xcd_remap(d, gx * gy * gridDim.z);
    Col0 = (wk % gx) * 128;
    int rest = wk / gx;
    Row0 = (rest % gy) * 128;
    bz = rest / gy;
  } else {
    Row0 = blockIdx.y * 128; Col0 = blockIdx.x * 128; bz = blockIdx.z;
  }
  const int gcol = ((l & 7) ^ (l >> 3)) * 8;

  const int srow = w * 32 + (l >> 3);
  const u16* baseA = A + (size_t)bz * sA + (size_t)(Row0 + srow) * lda + gcol;
  const u16* baseB = Bt + (size_t)bz * sB + (size_t)(Col0 + srow) * ldb + gcol;

  f32x4 acc[4][4];
  const f32x4 zero = {0.f, 0.f, 0.f, 0.f};
#pragma unroll
  for (int m = 0; m < 4; ++m)
#pragma unroll
    for (int n = 0; n < 4; ++n) acc[m][n] = zero;

#pragma unroll
  for (int k0 = 0; k0 < K; k0 += 64) {
    __syncthreads();
#pragma unroll
    for (int i = 0; i < 4; ++i) {
      gl2lds16(baseA + (size_t)(i * 8) * lda + k0, &lsA[w * 2048 + i * 512]);
      gl2lds16(baseB + (size_t)(i * 8) * ldb + k0, &lsB[w * 2048 + i * 512]);
    }
    __syncthreads();
#pragma unroll
    for (int kk = 0; kk < 64; kk += 32) {
      f16x8 af[4], bfv[4];
#pragma unroll
      for (int m = 0; m < 4; ++m)
        af[m] = ldf16(&lsA[swz(wm * 64 + m * 16 + lr, kk + 8 * lg)]);
#pragma unroll
      for (int n = 0; n < 4; ++n)
        bfv[n] = ldf16(&lsB[swz(wn * 64 + n * 16 + lr, kk + 8 * lg)]);
#pragma unroll
      for (int m = 0; m < 4; ++m)
#pragma unroll
        for (int n = 0; n < 4; ++n) acc[m][n] = mfma_f16(af[m], bfv[n], acc[m][n]);
    }
  }

  if constexpr (OUT16) {
    u16* Cb = (u16*)Cp + (size_t)bz * sC;
#pragma unroll
    for (int p = 0; p < 2; ++p) {
      __syncthreads();
      if (wm == p) {
#pragma unroll
        for (int m = 0; m < 4; ++m)
#pragma unroll
          for (int n = 0; n < 4; ++n) {
            int col = wn * 64 + n * 16 + lr;
            float bv = bias ? bias[Col0 + col] : 0.f;
#pragma unroll
            for (int r = 0; r < 4; ++r)
              lds[(m * 16 + lg * 4 + r) * 136 + col] = f2h(acc[m][n][r] * scale + bv);
          }
      }
      __syncthreads();
#pragma unroll
      for (int it = 0; it < 4; ++it) {
        int cid = it * 256 + tid;
        int rl = cid >> 4, cc = (cid & 15) * 8;
        u16x8 vv = *(u16x8*)&lds[rl * 136 + cc];
        *(u16x8*)&Cb[(size_t)(Row0 + p * 64 + rl) * ldc + Col0 + cc] = vv;
      }
    }
  } else {
    float* Cb = (float*)Cp + (size_t)bz * sC;
    float* ldsF = (float*)lds;  // [32][132] fp32
#pragma unroll
    for (int q = 0; q < 4; ++q) {
      __syncthreads();
      if (wm == (q >> 1)) {
        int mBase = (q & 1) * 2;
#pragma unroll
        for (int mi = 0; mi < 2; ++mi) {
          int m = mBase + mi;
#pragma unroll
          for (int n = 0; n < 4; ++n) {
            int col = wn * 64 + n * 16 + lr;
            float bv = bias ? bias[Col0 + col] : 0.f;
#pragma unroll
            for (int r = 0; r < 4; ++r)
              ldsF[(mi * 16 + lg * 4 + r) * 132 + col] = acc[m][n][r] * scale + bv;
          }
        }
      }
      __syncthreads();
#pragma unroll
      for (int it = 0; it < 4; ++it) {
        int cid = it * 256 + tid;
        int rw = cid >> 5, c4 = (cid & 31) * 4;
        float4 v = *(float4*)&ldsF[rw * 132 + c4];
        *(float4*)&Cb[(size_t)(Row0 + q * 32 + rw) * ldc + Col0 + c4] = v;
      }
    }
  }
}

// ---------------- fused temporal attention (fp16), one block per (b,c) ----------------
__global__ __launch_bounds__(256)
void attn_t_kernel(const u16* __restrict__ QK, const u16* __restrict__ Vb,
                   u16* __restrict__ O) {
  __shared__ u16 qs[32 * 520];
  __shared__ u16 ks[32 * 520];
  __shared__ u16 vT[512 * 40];
  __shared__ float Sf[32 * 36];
  __shared__ u16 Pf[32 * 40];

  const int tid = threadIdx.x;
  const int bc = blockIdx.x;  // b*1024 + c
  const int w = tid >> 6, l = tid & 63, lr = l & 15, lg = l >> 4;
  const int wr = w >> 1, wc = w & 1;
  const size_t base = (size_t)(bc >> 10) * 32768 + (bc & 1023);

#pragma unroll
  for (int i = 0; i < 8; ++i) {
    int t = w * 8 + i;
    const u16* rb = QK + (base + (size_t)t * 1024) * 1024;
    gl2lds16(rb + l * 8, &qs[t * 520]);
    gl2lds16(rb + 512 + l * 8, &ks[t * 520]);
  }
  {  // V staging, t-major lanes: conflict-free vT writes
    const int t = tid & 31;
    const int db0 = (tid >> 5) * 8;
    const u16* vrow = Vb + (base + (size_t)t * 1024) * 512;
#pragma unroll
    for (int j = 0; j < 8; ++j) {
      int db = db0 + j;
      u16x8 vv = *(const u16x8*)(vrow + db * 8);
#pragma unroll
      for (int e = 0; e < 8; ++e) vT[(db * 8 + e) * 40 + t] = vv[e];
    }
  }
  __syncthreads();

  f32x4 sacc = {0.f, 0.f, 0.f, 0.f};
#pragma unroll
  for (int kk = 0; kk < 512; kk += 32)
    sacc = mfma_f16(ldf16(&qs[(wr * 16 + lr) * 520 + kk + 8 * lg]),
                    ldf16(&ks[(wc * 16 + lr) * 520 + kk + 8 * lg]), sacc);
#pragma unroll
  for (int r = 0; r < 4; ++r)
    Sf[(wr * 16 + lg * 4 + r) * 36 + wc * 16 + lr] = sacc[r] * 0.125f;
  __syncthreads();

  {  // parallel softmax: 8 threads per row
    const int row = tid >> 3, c0 = (tid & 7) * 4;
    float4 sv = *(float4*)&Sf[row * 36 + c0];
    float mx = fmaxf(fmaxf(sv.x, sv.y), fmaxf(sv.z, sv.w));
#pragma unroll
    for (int o = 1; o < 8; o <<= 1) mx = fmaxf(mx, __shfl_xor(mx, o, 64));
    float e0 = __expf(sv.x - mx), e1 = __expf(sv.y - mx);
    float e2 = __expf(sv.z - mx), e3 = __expf(sv.w - mx);
    float sum = e0 + e1 + e2 + e3;
#pragma unroll
    for (int o = 1; o < 8; o <<= 1) sum += __shfl_xor(sum, o, 64);
    float inv = 1.f / sum;
    u16x4 p4 = {f2h(e0 * inv), f2h(e1 * inv), f2h(e2 * inv), f2h(e3 * inv)};
    *(u16x4*)&Pf[row * 40 + c0] = p4;
  }
  __syncthreads();

  {  // O = P @ V, staged into qs for coalesced u16x8 stores
    const int mr = w >> 1, nh = w & 1;
    f16x8 ap = ldf16(&Pf[(mr * 16 + lr) * 40 + 8 * lg]);
#pragma unroll
    for (int j = 0; j < 16; ++j) {
      int nc = (nh * 16 + j) * 16;
      f32x4 o = {0.f, 0.f, 0.f, 0.f};
      o = mfma_f16(ap, ldf16(&vT[(nc + lr) * 40 + 8 * lg]), o);
#pragma unroll
      for (int r = 0; r < 4; ++r)
        qs[(mr * 16 + lg * 4 + r) * 520 + nc + lr] = f2h(o[r]);
    }
  }
  __syncthreads();
#pragma unroll
  for (int it = 0; it < 8; ++it) {
    int cid = it * 256 + tid;
    int t = cid >> 6, col = (cid & 63) * 8;
    u16x8 vv = *(u16x8*)&qs[t * 520 + col];
    *(u16x8*)&O[(base + (size_t)t * 1024) * 512 + col] = vv;
  }
}

// ---------------- row softmax over 1024 fp16: one wave per row, no barriers/LDS ----------
__global__ __launch_bounds__(256)
void softmax16_kernel(u16* __restrict__ S) {
  const int w = threadIdx.x >> 6, l = threadIdx.x & 63;
  u16* p = S + (((size_t)blockIdx.x * 4 + w) << 10) + l * 16;
  u16x8 a = *(u16x8*)p;
  u16x8 b = *(u16x8*)(p + 8);
  float v[16];
#pragma unroll
  for (int e = 0; e < 8; ++e) { v[e] = h2f(a[e]); v[8 + e] = h2f(b[e]); }
  float m = v[0];
#pragma unroll
  for (int e = 1; e < 16; ++e) m = fmaxf(m, v[e]);
#pragma unroll
  for (int o = 1; o < 64; o <<= 1) m = fmaxf(m, __shfl_xor(m, o, 64));
  float s = 0.f;
#pragma unroll
  for (int e = 0; e < 16; ++e) { v[e] = __expf(v[e] - m); s += v[e]; }
#pragma unroll
  for (int o = 1; o < 64; o <<= 1) s += __shfl_xor(s, o, 64);
  const float inv = 1.f / s;
  u16x8 oa, ob;
#pragma unroll
  for (int e = 0; e < 8; ++e) { oa[e] = f2h(v[e] * inv); ob[e] = f2h(v[8 + e] * inv); }
  *(u16x8*)p = oa;
  *(u16x8*)(p + 8) = ob;
}

extern "C" void kernel_launch(void* const* d_in, const int* in_sizes, int n_in,
                              void* d_out, int out_size, void* d_ws, size_t ws_size,
                              hipStream_t stream) {
  (void)in_sizes; (void)n_in; (void)out_size; (void)ws_size;
  const float* x      = (const float*)d_in[0];
  const float* gam_t  = (const float*)d_in[1];
  const float* bet_t  = (const float*)d_in[2];
  const float* wqkv_t = (const float*)d_in[3];
  const float* wout_t = (const float*)d_in[4];
  const float* bout_t = (const float*)d_in[5];
  const float* gam_s  = (const float*)d_in[6];
  const float* bet_s  = (const float*)d_in[7];
  const float* wqkv_s = (const float*)d_in[8];
  const float* wout_s = (const float*)d_in[9];
  const float* bout_s = (const float*)d_in[10];
  float* out = (float*)d_out;

  char* ws = (char*)d_ws;
  size_t off = 0;
  auto alloc = [&](size_t bytes) -> char* {
    char* p = ws + off;
    off = (off + bytes + 255) & ~(size_t)255;
    return p;
  };
  // Total ~392 MiB. Aliases: h = S region; out1 = QK first half; Vt = Vb slot.
  u16* wqkvT_t = (u16*)alloc((size_t)1536 * 512 * 2);
  u16* woutT_t = (u16*)alloc((size_t)512 * 512 * 2);
  u16* wqkvT_s = (u16*)alloc((size_t)1536 * 512 * 2);
  u16* woutT_s = (u16*)alloc((size_t)512 * 512 * 2);
  u16* QK      = (u16*)alloc((size_t)65536 * 1024 * 2);      // 128 MiB
  u16* Vb      = (u16*)alloc((size_t)65536 * 512 * 2);       //  64 MiB (temporal V / spatial Vt)
  u16* attnO   = (u16*)alloc((size_t)65536 * 512 * 2);       //  64 MiB
  u16* S       = (u16*)alloc((size_t)64 * 1024 * 1024 * 2);  // 128 MiB (single pass)
  u16* h       = S;    // LN output (64 MiB), dead before S is written
  u16* out1    = QK;   // temporal block output fp16 (64 MiB)
  u16* Vt      = Vb;   // spatial V transposed [bt][512][1024]

  const dim3 blk(256);

  wT_all_kernel<<<1024, blk, 0, stream>>>(wqkv_t, wout_t, wqkv_s, wout_s,
                                          wqkvT_t, woutT_t, wqkvT_s, woutT_s);

  // ---- temporal ----
  ln_kernel<<<16384, blk, 0, stream>>>(x, gam_t, bet_t, h);
  gemm_qkv<512><<<dim3(12, 512, 1), blk, 0, stream>>>(h, wqkvT_t, QK, Vb, 512, 512);
  attn_t_kernel<<<2048, blk, 0, stream>>>(QK, Vb, attnO);
  gemm_bt<true, 1, 512><<<dim3(4, 512, 1), blk, 0, stream>>>(
      attnO, woutT_t, out1, bout_t, 512, 512, 512, 0, 0, 0, 1.f);

  // ---- spatial (Q|K straight; V transposed by dedicated kernel; single chunk) ----
  ln16_kernel<<<16384, blk, 0, stream>>>(out1, gam_s, bet_s, h);
  gemm_qk_s<512><<<dim3(8, 512, 1), blk, 0, stream>>>(h, wqkvT_s, QK, 512, 512);
  gemm_vt_s<512><<<dim3(4, 512, 1), blk, 0, stream>>>(
      h, wqkvT_s + (size_t)1024 * 512, Vt, 512, 512);

  gemm_bt<true, 2, 512><<<dim3(8, 8, 64), blk, 0, stream>>>(
      QK, QK + 512, S, nullptr, 1024, 1024, 1024,
      1024LL * 1024, 1024LL * 1024, 1024LL * 1024, 0.125f);
  softmax16_kernel<<<16384, blk, 0, stream>>>(S);
  gemm_bt<true, 2, 1024><<<dim3(4, 8, 64), blk, 0, stream>>>(
      S, Vt, attnO, nullptr, 1024, 1024, 512,
      1024LL * 1024, 512LL * 1024, 1024LL * 512, 1.f);

  gemm_bt<false, 1, 512><<<dim3(4, 512, 1), blk, 0, stream>>>(
      attnO, woutT_s, out, bout_s, 512, 512, 512, 0, 0, 0, 1.f);
}